// Round 9
// baseline (276.442 us; speedup 1.0000x reference)
//
#include <hip/hip_runtime.h>

#define NTOK 3072
#define DM   1280
#define NH   16
#define HD   80
#define HDS  96    // padded head-dim stride for Q/K: 192B = 3 cache lines -> every row 64B-aligned
#define KVB  64
#define NSEG 8
#define QKVC 3840

typedef __attribute__((ext_vector_type(4))) float  f32x4;
typedef __attribute__((ext_vector_type(8))) __bf16 bf16x8;
typedef __attribute__((ext_vector_type(8))) unsigned short ushort8;
typedef __attribute__((ext_vector_type(4))) unsigned short ushort4v;
typedef __attribute__((ext_vector_type(2))) unsigned int  u32x2;

static __device__ __forceinline__ unsigned short f2bf(float f){
  union{float f; unsigned int u;} v; v.f=f;
  unsigned int r = v.u + 0x7fffu + ((v.u>>16)&1u);
  return (unsigned short)(r>>16);
}
static __device__ __forceinline__ float bf2f(unsigned short u){
  union{unsigned int i; float f;} v; v.i = ((unsigned int)u)<<16; return v.f;
}
static __device__ __forceinline__ void gload_lds16(const void* g, void* l){
  __builtin_amdgcn_global_load_lds((const __attribute__((address_space(1))) void*)g,
                                   (__attribute__((address_space(3))) void*)l, 16, 0, 0);
}

// ---------------- elementwise cast f32 -> bf16 ----------------
__global__ void cast_f32_bf16(const float* __restrict__ src, unsigned short* __restrict__ dst, int n){
  int i = (blockIdx.x*256 + threadIdx.x)*4;
  if (i >= n) return;
  f32x4 v = *reinterpret_cast<const f32x4*>(&src[i]);
  ushort4v o;
  o[0]=f2bf(v[0]); o[1]=f2bf(v[1]); o[2]=f2bf(v[2]); o[3]=f2bf(v[3]);
  *reinterpret_cast<ushort4v*>(&dst[i]) = o;
}

// ---------------- tiled transpose + cast: src[R][C] f32 -> dst[C][R] bf16 ----------------
__global__ void transpose_cast(const float* __restrict__ src, unsigned short* __restrict__ dst, int R, int C){
  __shared__ unsigned short tile[32][33];
  int c0 = blockIdx.x*32, r0 = blockIdx.y*32;
  int tx = threadIdx.x, ty = threadIdx.y;   // 32 x 8
  #pragma unroll
  for (int i=0;i<4;i++){
    int r = r0 + ty + i*8;
    tile[ty+i*8][tx] = f2bf(src[(size_t)r*C + c0 + tx]);
  }
  __syncthreads();
  #pragma unroll
  for (int i=0;i<4;i++){
    int c = c0 + ty + i*8;
    dst[(size_t)c*R + r0 + tx] = tile[tx][ty+i*8];
  }
}

// ---------------- per-head V transpose: qkv[n][2*DM + h*80 + d] -> Vt[h][d][n] ----------------
__global__ void transpose_v(const unsigned short* __restrict__ qkv, unsigned short* __restrict__ Vt){
  __shared__ unsigned short tile[32][33];
  int n0 = blockIdx.x*32, d0 = blockIdx.y*32, h = blockIdx.z;
  int tx = threadIdx.x, ty = threadIdx.y;   // 32 x 8
  #pragma unroll
  for (int i=0;i<4;i++){
    int n = n0 + ty + i*8;
    int d = d0 + tx;
    tile[ty+i*8][tx] = (d < HD) ? qkv[(size_t)n*QKVC + 2*DM + h*HD + d] : (unsigned short)0;
  }
  __syncthreads();
  #pragma unroll
  for (int i=0;i<4;i++){
    int d = d0 + ty + i*8;
    if (d < HD) Vt[((size_t)h*HD + d)*NTOK + n0 + tx] = tile[tx][ty+i*8];
  }
}

// ---------------- 2-phase pipelined bf16 GEMM: C = A[M][Kd] * Bt[Ncol][Kd]^T + bias ----------------
// 1D grid + bijective XCD swizzle (nwg % 8 == 0 for both call sites)
template<int OUT_BF16>
__global__ __launch_bounds__(256) void gemm_bt(
    const unsigned short* __restrict__ A,
    const unsigned short* __restrict__ Bt,
    const float* __restrict__ bias,
    unsigned short* __restrict__ Cb,
    float* __restrict__ Cf,
    int M, int Ncol, int Kd, int nbn)
{
  __shared__ unsigned short As[2][128*32];
  __shared__ unsigned short Bs[2][128*32];
  const int tid  = threadIdx.x;
  const int lane = tid & 63, wave = tid >> 6;
  const int wr = wave >> 1, wc = wave & 1;
  const int cpx = gridDim.x >> 3;
  const int id  = (blockIdx.x & 7)*cpx + (blockIdx.x >> 3);
  const int bm = id / nbn, bn = id % nbn;
  const f32x4 vzero = {0.f,0.f,0.f,0.f};

  f32x4 acc[4][4];
  #pragma unroll
  for (int i=0;i<4;i++)
    #pragma unroll
    for (int j=0;j<4;j++) acc[i][j] = vzero;

  const int rsub = lane>>2;          // 0..15
  const int kc   = (lane&3)*8;       // 0,8,16,24
  const unsigned short* Ab = A  + (size_t)(bm*128 + wave*32 + rsub)*Kd + kc;
  const unsigned short* Bb = Bt + (size_t)(bn*128 + wave*32 + rsub)*Kd + kc;

  // prologue: stage tile 0
  #pragma unroll
  for (int i=0;i<2;i++){
    gload_lds16(Ab + (size_t)i*16*Kd, &As[0][(wave*2+i)*512]);
    gload_lds16(Bb + (size_t)i*16*Kd, &Bs[0][(wave*2+i)*512]);
  }
  __syncthreads();

  int cur = 0;
  for (int k0=32; k0<Kd; k0+=32){
    #pragma unroll
    for (int i=0;i<2;i++){
      gload_lds16(Ab + (size_t)i*16*Kd + k0, &As[cur^1][(wave*2+i)*512]);
      gload_lds16(Bb + (size_t)i*16*Kd + k0, &Bs[cur^1][(wave*2+i)*512]);
    }
    bf16x8 a[4], b[4];
    #pragma unroll
    for (int mf=0; mf<4; mf++)
      a[mf] = *reinterpret_cast<const bf16x8*>(&As[cur][(wr*64 + mf*16 + (lane&15))*32 + ((lane>>4)<<3)]);
    #pragma unroll
    for (int nf=0; nf<4; nf++)
      b[nf] = *reinterpret_cast<const bf16x8*>(&Bs[cur][(wc*64 + nf*16 + (lane&15))*32 + ((lane>>4)<<3)]);
    #pragma unroll
    for (int mf=0; mf<4; mf++)
      #pragma unroll
      for (int nf=0; nf<4; nf++)
        acc[mf][nf] = __builtin_amdgcn_mfma_f32_16x16x32_bf16(a[mf], b[nf], acc[mf][nf], 0,0,0);
    __syncthreads();
    cur ^= 1;
  }
  { // final tile
    bf16x8 a[4], b[4];
    #pragma unroll
    for (int mf=0; mf<4; mf++)
      a[mf] = *reinterpret_cast<const bf16x8*>(&As[cur][(wr*64 + mf*16 + (lane&15))*32 + ((lane>>4)<<3)]);
    #pragma unroll
    for (int nf=0; nf<4; nf++)
      b[nf] = *reinterpret_cast<const bf16x8*>(&Bs[cur][(wc*64 + nf*16 + (lane&15))*32 + ((lane>>4)<<3)]);
    #pragma unroll
    for (int mf=0; mf<4; mf++)
      #pragma unroll
      for (int nf=0; nf<4; nf++)
        acc[mf][nf] = __builtin_amdgcn_mfma_f32_16x16x32_bf16(a[mf], b[nf], acc[mf][nf], 0,0,0);
  }

  const int crow0 = bm*128 + wr*64;
  const int ccol0 = bn*128 + wc*64;
  #pragma unroll
  for (int nf=0; nf<4; nf++){
    int col = ccol0 + nf*16 + (lane&15);
    float bv = bias[col];
    #pragma unroll
    for (int mf=0; mf<4; mf++){
      #pragma unroll
      for (int r=0;r<4;r++){
        int row = crow0 + mf*16 + ((lane>>4)<<2) + r;
        float v = acc[mf][nf][r] + bv;
        if (OUT_BF16) Cb[(size_t)row*Ncol + col] = f2bf(v);
        else          Cf[(size_t)row*Ncol + col] = v;
      }
    }
  }
}

// ---------------- RoPE + repack to [H][N][96] (pad 80->96 with zeros) ----------------
__global__ void rope_repack(const unsigned short* __restrict__ qkv,
                            const float* __restrict__ cosNK, const float* __restrict__ sinNK,
                            unsigned short* __restrict__ Qr, unsigned short* __restrict__ Kr)
{
  int idx = blockIdx.x*256 + threadIdx.x;
  if (idx >= NH*NTOK*HDS) return;
  int k  = idx % HDS;
  int nh = idx / HDS;
  int n  = nh % NTOK;
  int h  = nh / NTOK;
  size_t dsti = (size_t)(h*NTOK + n)*HDS + k;
  if (k >= HD){ Qr[dsti]=0; Kr[dsti]=0; return; }
  float c = cosNK[n*HD + k], s = sinNK[n*HD + k];
  int   kp  = (k < 40) ? (k+40) : (k-40);
  float sgn = (k < 40) ? -1.f : 1.f;
  size_t base = (size_t)n*QKVC + h*HD;
  float q   = bf2f(qkv[base + k]);
  float qp  = bf2f(qkv[base + kp]);
  float kk  = bf2f(qkv[base + DM + k]);
  float kkp = bf2f(qkv[base + DM + kp]);
  Qr[dsti] = f2bf(q*c  + sgn*qp*s);
  Kr[dsti] = f2bf(kk*c + sgn*kkp*s);
}

// ---------------- segment-masked flash attention: swapped QK^T, lane-local softmax,
// ---------------- 8 waves/block: 4 q-slices x 2 k-parity halves, in-LDS flash merge ----------------
#define ANB  ((NTOK/64)*NH)   // 768 blocks
__global__ __launch_bounds__(512) void attn_kernel(
    const unsigned short* __restrict__ Qr,
    const unsigned short* __restrict__ Kr,
    const unsigned short* __restrict__ Vt,
    const int* __restrict__ cu,
    unsigned short* __restrict__ attn_out)
{
  __shared__ unsigned short Ps[8*16*KVB];   // 16 KB: per-wave 2 KB slice (16 rows x 64 k), XOR-swizzled
  __shared__ float Comb[4][64][23];         // 23.5 KB: per q-slice per lane {20 O, m, l} (stride 23: conflict-free)

  // head-chunked XCD swizzle: XCD x owns ids [x*96, (x+1)*96) = heads {2x, 2x+1}, all q-blocks.
  const int bx  = blockIdx.x;
  const int id  = (bx & 7)*(ANB/8) + (bx >> 3);
  const int h   = id / (NTOK/64);
  const int q0  = (id % (NTOK/64))*64;
  const int tid = threadIdx.x;
  const int lane = tid & 63, wave = tid >> 6;   // wave 0..7
  const int qsub = wave & 3, half = wave >> 2;  // q-slice, k-parity
  const int l16 = lane & 15, g16 = lane >> 4;
  const int qrow = q0 + qsub*16 + l16;          // this lane's q-row
  const f32x4 vzero = {0.f,0.f,0.f,0.f};

  // per-lane segment bounds + per-WAVE k-range (16 rows of this q-slice only)
  const int rowA = q0 + qsub*16, rowB = rowA + 15;
  int seg = 0, sA = 0, sB = 0;
  #pragma unroll
  for (int j=1;j<NSEG;j++){
    int c = cu[j];
    seg += (c <= qrow) ? 1 : 0;
    sA  += (c <= rowA) ? 1 : 0;
    sB  += (c <= rowB) ? 1 : 0;
  }
  const int rst = cu[seg], ren = cu[seg+1];
  const int kminW = cu[sA], kmaxW = cu[sB+1];
  const int kt0w = kminW & ~(KVB-1);

  // Q fragments in registers (B-operand: row = own q, k-slice = g16*8)
  bf16x8 bq[3];
  {
    const unsigned short* qsrc = Qr + ((size_t)h*NTOK + qrow)*HDS;
    #pragma unroll
    for (int ds=0; ds<3; ds++)
      bq[ds] = *reinterpret_cast<const bf16x8*>(&qsrc[ds*32 + g16*8]);
  }

  f32x4 accO[5];
  #pragma unroll
  for (int i=0;i<5;i++) accO[i] = vzero;
  float m_r = -1e30f, l_r = 0.f;
  const float scale = 0.11180339887498948f;  // 1/sqrt(80)

  char* const psb = (char*)Ps + wave*2048;   // wave-private 16x64 bf16 slice
  const int pswz  = (l16 & 7) << 4;

  // this wave's tiles: parity `half` within [kt0w, kmaxW)
  for (int kt = kt0w + half*KVB; kt < kmaxW; kt += 2*KVB){
    // V fragments (A-operand: row = d, k-slice = g16*8) — issue early, use late
    ushort8 vreg[2][5];
    #pragma unroll
    for (int ks=0; ks<2; ks++)
      #pragma unroll
      for (int cf=0; cf<5; cf++)
        vreg[ks][cf] = *reinterpret_cast<const ushort8*>(
            &Vt[((size_t)h*HD + cf*16 + l16)*NTOK + kt + ks*32 + g16*8]);

    // S^T = K Q^T : accST[f] rows k = f*16 + g16*4 + r, col q = l16
    const unsigned short* ksrc = Kr + ((size_t)h*NTOK + kt)*HDS;
    f32x4 accST[4];
    #pragma unroll
    for (int i=0;i<4;i++) accST[i] = vzero;
    #pragma unroll
    for (int ds=0; ds<3; ds++){
      #pragma unroll
      for (int f=0; f<4; f++){
        bf16x8 ak = *reinterpret_cast<const bf16x8*>(&ksrc[(size_t)(f*16 + l16)*HDS + ds*32 + g16*8]);
        accST[f] = __builtin_amdgcn_mfma_f32_16x16x32_bf16(ak, bq[ds], accST[f], 0,0,0);
      }
    }

    // lane-local masked online softmax (row = qrow; 16 scores per lane)
    float mx = -1e30f;
    #pragma unroll
    for (int f=0; f<4; f++){
      #pragma unroll
      for (int r=0; r<4; r++){
        int kcol = kt + f*16 + g16*4 + r;
        bool ok = (kcol >= rst) && (kcol < ren);
        float s = accST[f][r]*scale;
        accST[f][r] = ok ? s : -3e38f;       // sentinel: exp(sent - mnew) == 0 exactly
        mx = fmaxf(mx, accST[f][r]);
      }
    }
    mx = fmaxf(mx, __shfl_xor(mx, 16));
    mx = fmaxf(mx, __shfl_xor(mx, 32));
    const float mnew  = fmaxf(m_r, mx);
    const float alpha = __expf(m_r - mnew);
    m_r = mnew;
    float lsum = 0.f;
    #pragma unroll
    for (int f=0; f<4; f++){
      #pragma unroll
      for (int r=0; r<4; r++){
        float e = __expf(accST[f][r] - mnew);
        accST[f][r] = e;
        lsum += e;
      }
    }
    lsum += __shfl_xor(lsum, 16);
    lsum += __shfl_xor(lsum, 32);
    l_r = l_r*alpha + lsum;
    #pragma unroll
    for (int cf=0; cf<5; cf++) accO[cf] *= alpha;

    // P -> Ps (bf16, wave-private, swizzled): lane writes k = 16f + 4*g16 + 0..3 of row l16
    #pragma unroll
    for (int f=0; f<4; f++){
      u32x2 pk;
      pk[0] = (unsigned int)f2bf(accST[f][0]) | ((unsigned int)f2bf(accST[f][1]) << 16);
      pk[1] = (unsigned int)f2bf(accST[f][2]) | ((unsigned int)f2bf(accST[f][3]) << 16);
      *reinterpret_cast<u32x2*>(psb + ((l16*128 + f*32 + g16*8) ^ pswz)) = pk;
    }

    // O^T += V^T P^T : a = Vt rows (d), b = Ps rows (own q), out D[d][q]
    #pragma unroll
    for (int ks=0; ks<2; ks++){
      bf16x8 bp = *reinterpret_cast<const bf16x8*>(psb + ((l16*128 + ks*64 + g16*16) ^ pswz));
      #pragma unroll
      for (int cf=0; cf<5; cf++){
        bf16x8 av = __builtin_bit_cast(bf16x8, vreg[ks][cf]);
        accO[cf] = __builtin_amdgcn_mfma_f32_16x16x32_bf16(av, bp, accO[cf], 0,0,0);
      }
    }
  }

  // flash merge of the two k-parity halves via LDS
  if (half == 1){
    float* dst = &Comb[qsub][lane][0];
    #pragma unroll
    for (int cf=0; cf<5; cf++)
      #pragma unroll
      for (int r=0; r<4; r++) dst[cf*4+r] = accO[cf][r];
    dst[20] = m_r; dst[21] = l_r;
  }
  __syncthreads();
  if (half == 0){
    const float* src = &Comb[qsub][lane][0];
    const float m1 = src[20], l1 = src[21];
    const float M  = fmaxf(m_r, m1);
    const float a0 = __expf(m_r - M), a1 = __expf(m1 - M);
    const float inv = 1.f / (l_r*a0 + l1*a1);
    #pragma unroll
    for (int cf=0; cf<5; cf++){
      ushort4v o;
      #pragma unroll
      for (int r=0;r<4;r++) o[r] = f2bf((accO[cf][r]*a0 + src[cf*4+r]*a1)*inv);
      *reinterpret_cast<ushort4v*>(&attn_out[(size_t)qrow*DM + h*HD + cf*16 + g16*4]) = o;
    }
  }
}

extern "C" void kernel_launch(void* const* d_in, const int* in_sizes, int n_in,
                              void* d_out, int out_size, void* d_ws, size_t ws_size,
                              hipStream_t stream)
{
  const float* hidden = (const float*)d_in[0];
  const int*   cu     = (const int*)  d_in[1];
  const float* cosNK  = (const float*)d_in[2];
  const float* sinNK  = (const float*)d_in[3];
  const float* qkv_w  = (const float*)d_in[4];
  const float* qkv_b  = (const float*)d_in[5];
  const float* proj_w = (const float*)d_in[6];
  const float* proj_b = (const float*)d_in[7];
  float* out = (float*)d_out;

  char* w = (char*)d_ws;
  unsigned short* hid_bf  = (unsigned short*)w;  w += (size_t)NTOK*DM*2;      // aliased by attn_bf later
  unsigned short* qkvwT   = (unsigned short*)w;  w += (size_t)QKVC*DM*2;      // aliased by Vt later
  unsigned short* projwT  = (unsigned short*)w;  w += (size_t)DM*DM*2;
  unsigned short* qkv_bf  = (unsigned short*)w;  w += (size_t)NTOK*QKVC*2;
  unsigned short* Qr      = (unsigned short*)w;  w += (size_t)NH*NTOK*HDS*2;
  unsigned short* Kr      = (unsigned short*)w;  w += (size_t)NH*NTOK*HDS*2;
  unsigned short* Vt      = qkvwT;    // reuse: qkvwT dead after QKV GEMM
  unsigned short* attn_bf = hid_bf;   // reuse: hid_bf dead after QKV GEMM

  cast_f32_bf16<<<(NTOK*DM/4 + 255)/256, 256, 0, stream>>>(hidden, hid_bf, NTOK*DM);
  transpose_cast<<<dim3(QKVC/32, DM/32), dim3(32,8), 0, stream>>>(qkv_w, qkvwT, DM, QKVC);
  transpose_cast<<<dim3(DM/32,  DM/32), dim3(32,8), 0, stream>>>(proj_w, projwT, DM, DM);
  gemm_bt<1><<<dim3((NTOK/128)*(QKVC/128)), 256, 0, stream>>>(hid_bf, qkvwT, qkv_b, qkv_bf, nullptr, NTOK, QKVC, DM, QKVC/128);
  rope_repack<<<(NH*NTOK*HDS + 255)/256, 256, 0, stream>>>(qkv_bf, cosNK, sinNK, Qr, Kr);
  transpose_v<<<dim3(NTOK/32, 3, NH), dim3(32,8), 0, stream>>>(qkv_bf, Vt);
  attn_kernel<<<dim3(ANB), 512, 0, stream>>>(Qr, Kr, Vt, cu, attn_bf);
  gemm_bt<0><<<dim3((NTOK/128)*(DM/128)), 256, 0, stream>>>(attn_bf, projwT, proj_b, nullptr, out, NTOK, DM, DM, DM/128);
}

// Round 10
// 255.946 us; speedup vs baseline: 1.0801x; 1.0801x over previous
//
#include <hip/hip_runtime.h>

#define NTOK 3072
#define DM   1280
#define NH   16
#define HD   80
#define HDS  96    // padded head-dim stride for Q/K: 192B = 3 cache lines -> every row 64B-aligned
#define KVB  64
#define NSEG 8
#define QKVC 3840

typedef __attribute__((ext_vector_type(4))) float  f32x4;
typedef __attribute__((ext_vector_type(8))) __bf16 bf16x8;
typedef __attribute__((ext_vector_type(8))) unsigned short ushort8;
typedef __attribute__((ext_vector_type(4))) unsigned short ushort4v;
typedef __attribute__((ext_vector_type(2))) unsigned int  u32x2;

static __device__ __forceinline__ unsigned short f2bf(float f){
  union{float f; unsigned int u;} v; v.f=f;
  unsigned int r = v.u + 0x7fffu + ((v.u>>16)&1u);
  return (unsigned short)(r>>16);
}
static __device__ __forceinline__ float bf2f(unsigned short u){
  union{unsigned int i; float f;} v; v.i = ((unsigned int)u)<<16; return v.f;
}
static __device__ __forceinline__ void gload_lds16(const void* g, void* l){
  __builtin_amdgcn_global_load_lds((const __attribute__((address_space(1))) void*)g,
                                   (__attribute__((address_space(3))) void*)l, 16, 0, 0);
}

// ---------------- elementwise cast f32 -> bf16 ----------------
__global__ void cast_f32_bf16(const float* __restrict__ src, unsigned short* __restrict__ dst, int n){
  int i = (blockIdx.x*256 + threadIdx.x)*4;
  if (i >= n) return;
  f32x4 v = *reinterpret_cast<const f32x4*>(&src[i]);
  ushort4v o;
  o[0]=f2bf(v[0]); o[1]=f2bf(v[1]); o[2]=f2bf(v[2]); o[3]=f2bf(v[3]);
  *reinterpret_cast<ushort4v*>(&dst[i]) = o;
}

// ---------------- tiled transpose + cast: src[R][C] f32 -> dst[C][R] bf16 ----------------
__global__ void transpose_cast(const float* __restrict__ src, unsigned short* __restrict__ dst, int R, int C){
  __shared__ unsigned short tile[32][33];
  int c0 = blockIdx.x*32, r0 = blockIdx.y*32;
  int tx = threadIdx.x, ty = threadIdx.y;   // 32 x 8
  #pragma unroll
  for (int i=0;i<4;i++){
    int r = r0 + ty + i*8;
    tile[ty+i*8][tx] = f2bf(src[(size_t)r*C + c0 + tx]);
  }
  __syncthreads();
  #pragma unroll
  for (int i=0;i<4;i++){
    int c = c0 + ty + i*8;
    dst[(size_t)c*R + r0 + tx] = tile[tx][ty+i*8];
  }
}

// ---------------- per-head V transpose: qkv[n][2*DM + h*80 + d] -> Vt[h][d][n] ----------------
__global__ void transpose_v(const unsigned short* __restrict__ qkv, unsigned short* __restrict__ Vt){
  __shared__ unsigned short tile[32][33];
  int n0 = blockIdx.x*32, d0 = blockIdx.y*32, h = blockIdx.z;
  int tx = threadIdx.x, ty = threadIdx.y;   // 32 x 8
  #pragma unroll
  for (int i=0;i<4;i++){
    int n = n0 + ty + i*8;
    int d = d0 + tx;
    tile[ty+i*8][tx] = (d < HD) ? qkv[(size_t)n*QKVC + 2*DM + h*HD + d] : (unsigned short)0;
  }
  __syncthreads();
  #pragma unroll
  for (int i=0;i<4;i++){
    int d = d0 + ty + i*8;
    if (d < HD) Vt[((size_t)h*HD + d)*NTOK + n0 + tx] = tile[tx][ty+i*8];
  }
}

// ---------------- 2-phase pipelined bf16 GEMM: C = A[M][Kd] * Bt[Ncol][Kd]^T + bias ----------------
// 1D grid + bijective XCD swizzle (nwg % 8 == 0 for both call sites)
template<int OUT_BF16>
__global__ __launch_bounds__(256) void gemm_bt(
    const unsigned short* __restrict__ A,
    const unsigned short* __restrict__ Bt,
    const float* __restrict__ bias,
    unsigned short* __restrict__ Cb,
    float* __restrict__ Cf,
    int M, int Ncol, int Kd, int nbn)
{
  __shared__ unsigned short As[2][128*32];
  __shared__ unsigned short Bs[2][128*32];
  const int tid  = threadIdx.x;
  const int lane = tid & 63, wave = tid >> 6;
  const int wr = wave >> 1, wc = wave & 1;
  const int cpx = gridDim.x >> 3;
  const int id  = (blockIdx.x & 7)*cpx + (blockIdx.x >> 3);
  const int bm = id / nbn, bn = id % nbn;
  const f32x4 vzero = {0.f,0.f,0.f,0.f};

  f32x4 acc[4][4];
  #pragma unroll
  for (int i=0;i<4;i++)
    #pragma unroll
    for (int j=0;j<4;j++) acc[i][j] = vzero;

  const int rsub = lane>>2;          // 0..15
  const int kc   = (lane&3)*8;       // 0,8,16,24
  const unsigned short* Ab = A  + (size_t)(bm*128 + wave*32 + rsub)*Kd + kc;
  const unsigned short* Bb = Bt + (size_t)(bn*128 + wave*32 + rsub)*Kd + kc;

  // prologue: stage tile 0
  #pragma unroll
  for (int i=0;i<2;i++){
    gload_lds16(Ab + (size_t)i*16*Kd, &As[0][(wave*2+i)*512]);
    gload_lds16(Bb + (size_t)i*16*Kd, &Bs[0][(wave*2+i)*512]);
  }
  __syncthreads();

  int cur = 0;
  for (int k0=32; k0<Kd; k0+=32){
    #pragma unroll
    for (int i=0;i<2;i++){
      gload_lds16(Ab + (size_t)i*16*Kd + k0, &As[cur^1][(wave*2+i)*512]);
      gload_lds16(Bb + (size_t)i*16*Kd + k0, &Bs[cur^1][(wave*2+i)*512]);
    }
    bf16x8 a[4], b[4];
    #pragma unroll
    for (int mf=0; mf<4; mf++)
      a[mf] = *reinterpret_cast<const bf16x8*>(&As[cur][(wr*64 + mf*16 + (lane&15))*32 + ((lane>>4)<<3)]);
    #pragma unroll
    for (int nf=0; nf<4; nf++)
      b[nf] = *reinterpret_cast<const bf16x8*>(&Bs[cur][(wc*64 + nf*16 + (lane&15))*32 + ((lane>>4)<<3)]);
    #pragma unroll
    for (int mf=0; mf<4; mf++)
      #pragma unroll
      for (int nf=0; nf<4; nf++)
        acc[mf][nf] = __builtin_amdgcn_mfma_f32_16x16x32_bf16(a[mf], b[nf], acc[mf][nf], 0,0,0);
    __syncthreads();
    cur ^= 1;
  }
  { // final tile
    bf16x8 a[4], b[4];
    #pragma unroll
    for (int mf=0; mf<4; mf++)
      a[mf] = *reinterpret_cast<const bf16x8*>(&As[cur][(wr*64 + mf*16 + (lane&15))*32 + ((lane>>4)<<3)]);
    #pragma unroll
    for (int nf=0; nf<4; nf++)
      b[nf] = *reinterpret_cast<const bf16x8*>(&Bs[cur][(wc*64 + nf*16 + (lane&15))*32 + ((lane>>4)<<3)]);
    #pragma unroll
    for (int mf=0; mf<4; mf++)
      #pragma unroll
      for (int nf=0; nf<4; nf++)
        acc[mf][nf] = __builtin_amdgcn_mfma_f32_16x16x32_bf16(a[mf], b[nf], acc[mf][nf], 0,0,0);
  }

  const int crow0 = bm*128 + wr*64;
  const int ccol0 = bn*128 + wc*64;
  #pragma unroll
  for (int nf=0; nf<4; nf++){
    int col = ccol0 + nf*16 + (lane&15);
    float bv = bias[col];
    #pragma unroll
    for (int mf=0; mf<4; mf++){
      #pragma unroll
      for (int r=0;r<4;r++){
        int row = crow0 + mf*16 + ((lane>>4)<<2) + r;
        float v = acc[mf][nf][r] + bv;
        if (OUT_BF16) Cb[(size_t)row*Ncol + col] = f2bf(v);
        else          Cf[(size_t)row*Ncol + col] = v;
      }
    }
  }
}

// ---------------- RoPE + repack to [H][N][96], vectorized 8 elems/thread ----------------
// chunk c (8 elems): c 0..4 -> k<40 (pair +40, sgn -1); c 5..9 -> k in [40,80) (pair -40, sgn +1); c 10..11 -> zero pad
__global__ void rope_repack(const unsigned short* __restrict__ qkv,
                            const float* __restrict__ cosNK, const float* __restrict__ sinNK,
                            unsigned short* __restrict__ Qr, unsigned short* __restrict__ Kr)
{
  int idx = blockIdx.x*256 + threadIdx.x;
  if (idx >= NH*NTOK*12) return;
  int c  = idx % 12;
  int nh = idx / 12;
  int n  = nh % NTOK;
  int h  = nh / NTOK;
  unsigned short* qd = Qr + (size_t)(h*NTOK + n)*HDS + c*8;
  unsigned short* kd = Kr + (size_t)(h*NTOK + n)*HDS + c*8;
  if (c >= 10){
    ushort8 z = {0,0,0,0,0,0,0,0};
    *reinterpret_cast<ushort8*>(qd) = z;
    *reinterpret_cast<ushort8*>(kd) = z;
    return;
  }
  const int k0  = c*8;
  const int kp0 = (k0 < 40) ? (k0+40) : (k0-40);
  const float sgn = (k0 < 40) ? -1.f : 1.f;
  const size_t base = (size_t)n*QKVC + h*HD;
  ushort8 q  = *reinterpret_cast<const ushort8*>(&qkv[base + k0]);
  ushort8 qp = *reinterpret_cast<const ushort8*>(&qkv[base + kp0]);
  ushort8 kk = *reinterpret_cast<const ushort8*>(&qkv[base + DM + k0]);
  ushort8 kp = *reinterpret_cast<const ushort8*>(&qkv[base + DM + kp0]);
  f32x4 c0 = *reinterpret_cast<const f32x4*>(&cosNK[n*HD + k0]);
  f32x4 c1 = *reinterpret_cast<const f32x4*>(&cosNK[n*HD + k0 + 4]);
  f32x4 s0 = *reinterpret_cast<const f32x4*>(&sinNK[n*HD + k0]);
  f32x4 s1 = *reinterpret_cast<const f32x4*>(&sinNK[n*HD + k0 + 4]);
  ushort8 qo, ko;
  #pragma unroll
  for (int j=0;j<8;j++){
    float cj = (j<4) ? c0[j] : c1[j-4];
    float sj = (j<4) ? s0[j] : s1[j-4];
    qo[j] = f2bf(bf2f(q[j])*cj  + sgn*bf2f(qp[j])*sj);
    ko[j] = f2bf(bf2f(kk[j])*cj + sgn*bf2f(kp[j])*sj);
  }
  *reinterpret_cast<ushort8*>(qd) = qo;
  *reinterpret_cast<ushort8*>(kd) = ko;
}

// ---------------- segment-masked flash attention: swapped QK^T, lane-local softmax,
// ---------------- 2D balanced grid, 4 waves, per-wave k-range, no main-loop barriers ----------------
__global__ __launch_bounds__(256) void attn_kernel(
    const unsigned short* __restrict__ Qr,
    const unsigned short* __restrict__ Kr,
    const unsigned short* __restrict__ Vt,
    const int* __restrict__ cu,
    unsigned short* __restrict__ attn_out)
{
  __shared__ unsigned short Ps[4*16*KVB];   // 8 KB: per-wave 2 KB slice (16 rows x 64 k), XOR-swizzled

  const int h   = blockIdx.y;
  const int q0  = blockIdx.x*64;
  const int tid = threadIdx.x;
  const int lane = tid & 63, wave = tid >> 6;   // wave = q-slice 0..3
  const int l16 = lane & 15, g16 = lane >> 4;
  const int qrow = q0 + wave*16 + l16;          // this lane's q-row
  const f32x4 vzero = {0.f,0.f,0.f,0.f};

  // per-lane segment bounds + per-WAVE k-range (this wave's 16 rows only)
  const int rowA = q0 + wave*16, rowB = rowA + 15;
  int seg = 0, sA = 0, sB = 0;
  #pragma unroll
  for (int j=1;j<NSEG;j++){
    int c = cu[j];
    seg += (c <= qrow) ? 1 : 0;
    sA  += (c <= rowA) ? 1 : 0;
    sB  += (c <= rowB) ? 1 : 0;
  }
  const int rst = cu[seg], ren = cu[seg+1];
  const int kminW = cu[sA], kmaxW = cu[sB+1];
  const int kt0w = kminW & ~(KVB-1);

  // Q fragments in registers (B-operand: row = own q, k-slice = g16*8)
  bf16x8 bq[3];
  {
    const unsigned short* qsrc = Qr + ((size_t)h*NTOK + qrow)*HDS;
    #pragma unroll
    for (int ds=0; ds<3; ds++)
      bq[ds] = *reinterpret_cast<const bf16x8*>(&qsrc[ds*32 + g16*8]);
  }

  f32x4 accO[5];
  #pragma unroll
  for (int i=0;i<5;i++) accO[i] = vzero;
  float m_r = -1e30f, l_r = 0.f;
  const float scale = 0.11180339887498948f;  // 1/sqrt(80)

  char* const psb = (char*)Ps + wave*2048;   // wave-private 16x64 bf16 slice
  const int pswz  = (l16 & 7) << 4;

  for (int kt = kt0w; kt < kmaxW; kt += KVB){
    // V fragments (A-operand: row = d, k-slice = g16*8) — issue early, use late
    ushort8 vreg[2][5];
    #pragma unroll
    for (int ks=0; ks<2; ks++)
      #pragma unroll
      for (int cf=0; cf<5; cf++)
        vreg[ks][cf] = *reinterpret_cast<const ushort8*>(
            &Vt[((size_t)h*HD + cf*16 + l16)*NTOK + kt + ks*32 + g16*8]);

    // S^T = K Q^T : accST[f] rows k = f*16 + g16*4 + r, col q = l16
    const unsigned short* ksrc = Kr + ((size_t)h*NTOK + kt)*HDS;
    f32x4 accST[4];
    #pragma unroll
    for (int i=0;i<4;i++) accST[i] = vzero;
    #pragma unroll
    for (int ds=0; ds<3; ds++){
      #pragma unroll
      for (int f=0; f<4; f++){
        bf16x8 ak = *reinterpret_cast<const bf16x8*>(&ksrc[(size_t)(f*16 + l16)*HDS + ds*32 + g16*8]);
        accST[f] = __builtin_amdgcn_mfma_f32_16x16x32_bf16(ak, bq[ds], accST[f], 0,0,0);
      }
    }

    // lane-local masked online softmax (row = qrow; 16 scores per lane)
    float mx = -1e30f;
    #pragma unroll
    for (int f=0; f<4; f++){
      #pragma unroll
      for (int r=0; r<4; r++){
        int kcol = kt + f*16 + g16*4 + r;
        bool ok = (kcol >= rst) && (kcol < ren);
        float s = accST[f][r]*scale;
        accST[f][r] = ok ? s : -3e38f;       // sentinel: exp(sent - mnew) == 0 exactly
        mx = fmaxf(mx, accST[f][r]);
      }
    }
    mx = fmaxf(mx, __shfl_xor(mx, 16));
    mx = fmaxf(mx, __shfl_xor(mx, 32));
    const float mnew  = fmaxf(m_r, mx);
    const float alpha = __expf(m_r - mnew);
    m_r = mnew;
    float lsum = 0.f;
    #pragma unroll
    for (int f=0; f<4; f++){
      #pragma unroll
      for (int r=0; r<4; r++){
        float e = __expf(accST[f][r] - mnew);
        accST[f][r] = e;
        lsum += e;
      }
    }
    lsum += __shfl_xor(lsum, 16);
    lsum += __shfl_xor(lsum, 32);
    l_r = l_r*alpha + lsum;
    #pragma unroll
    for (int cf=0; cf<5; cf++) accO[cf] *= alpha;

    // P -> Ps (bf16, wave-private, swizzled): lane writes k = 16f + 4*g16 + 0..3 of row l16
    #pragma unroll
    for (int f=0; f<4; f++){
      u32x2 pk;
      pk[0] = (unsigned int)f2bf(accST[f][0]) | ((unsigned int)f2bf(accST[f][1]) << 16);
      pk[1] = (unsigned int)f2bf(accST[f][2]) | ((unsigned int)f2bf(accST[f][3]) << 16);
      *reinterpret_cast<u32x2*>(psb + ((l16*128 + f*32 + g16*8) ^ pswz)) = pk;
    }

    // O^T += V^T P^T : a = Vt rows (d), b = Ps rows (own q), out D[d][q]
    #pragma unroll
    for (int ks=0; ks<2; ks++){
      bf16x8 bp = *reinterpret_cast<const bf16x8*>(psb + ((l16*128 + ks*64 + g16*16) ^ pswz));
      #pragma unroll
      for (int cf=0; cf<5; cf++){
        bf16x8 av = __builtin_bit_cast(bf16x8, vreg[ks][cf]);
        accO[cf] = __builtin_amdgcn_mfma_f32_16x16x32_bf16(av, bp, accO[cf], 0,0,0);
      }
    }
  }

  // epilogue: lane holds O[qrow][d = cf*16 + g16*4 + r] -> packed 8B stores
  const float inv = 1.f / l_r;
  #pragma unroll
  for (int cf=0; cf<5; cf++){
    ushort4v o;
    #pragma unroll
    for (int r=0;r<4;r++) o[r] = f2bf(accO[cf][r]*inv);
    *reinterpret_cast<ushort4v*>(&attn_out[(size_t)qrow*DM + h*HD + cf*16 + g16*4]) = o;
  }
}

extern "C" void kernel_launch(void* const* d_in, const int* in_sizes, int n_in,
                              void* d_out, int out_size, void* d_ws, size_t ws_size,
                              hipStream_t stream)
{
  const float* hidden = (const float*)d_in[0];
  const int*   cu     = (const int*)  d_in[1];
  const float* cosNK  = (const float*)d_in[2];
  const float* sinNK  = (const float*)d_in[3];
  const float* qkv_w  = (const float*)d_in[4];
  const float* qkv_b  = (const float*)d_in[5];
  const float* proj_w = (const float*)d_in[6];
  const float* proj_b = (const float*)d_in[7];
  float* out = (float*)d_out;

  char* w = (char*)d_ws;
  unsigned short* hid_bf  = (unsigned short*)w;  w += (size_t)NTOK*DM*2;      // aliased by attn_bf later
  unsigned short* qkvwT   = (unsigned short*)w;  w += (size_t)QKVC*DM*2;      // aliased by Vt later
  unsigned short* projwT  = (unsigned short*)w;  w += (size_t)DM*DM*2;
  unsigned short* qkv_bf  = (unsigned short*)w;  w += (size_t)NTOK*QKVC*2;
  unsigned short* Qr      = (unsigned short*)w;  w += (size_t)NH*NTOK*HDS*2;
  unsigned short* Kr      = (unsigned short*)w;  w += (size_t)NH*NTOK*HDS*2;
  unsigned short* Vt      = qkvwT;    // reuse: qkvwT dead after QKV GEMM
  unsigned short* attn_bf = hid_bf;   // reuse: hid_bf dead after QKV GEMM

  cast_f32_bf16<<<(NTOK*DM/4 + 255)/256, 256, 0, stream>>>(hidden, hid_bf, NTOK*DM);
  transpose_cast<<<dim3(QKVC/32, DM/32), dim3(32,8), 0, stream>>>(qkv_w, qkvwT, DM, QKVC);
  transpose_cast<<<dim3(DM/32,  DM/32), dim3(32,8), 0, stream>>>(proj_w, projwT, DM, DM);
  gemm_bt<1><<<dim3((NTOK/128)*(QKVC/128)), 256, 0, stream>>>(hid_bf, qkvwT, qkv_b, qkv_bf, nullptr, NTOK, QKVC, DM, QKVC/128);
  rope_repack<<<(NH*NTOK*12 + 255)/256, 256, 0, stream>>>(qkv_bf, cosNK, sinNK, Qr, Kr);
  transpose_v<<<dim3(NTOK/32, 3, NH), dim3(32,8), 0, stream>>>(qkv_bf, Vt);
  attn_kernel<<<dim3(NTOK/64, NH), 256, 0, stream>>>(Qr, Kr, Vt, cu, attn_bf);
  gemm_bt<0><<<dim3((NTOK/128)*(DM/128)), 256, 0, stream>>>(attn_bf, projwT, proj_b, nullptr, out, NTOK, DM, DM, DM/128);
}

// Round 11
// 255.314 us; speedup vs baseline: 1.0828x; 1.0025x over previous
//
#include <hip/hip_runtime.h>

#define NTOK 3072
#define DM   1280
#define NH   16
#define HD   80
#define HDS  96    // padded head-dim stride for Q/K: 192B = 3 cache lines -> every row 64B-aligned
#define KVB  64
#define NSEG 8
#define QKVC 3840

typedef __attribute__((ext_vector_type(4))) float  f32x4;
typedef __attribute__((ext_vector_type(8))) __bf16 bf16x8;
typedef __attribute__((ext_vector_type(8))) unsigned short ushort8;
typedef __attribute__((ext_vector_type(4))) unsigned short ushort4v;
typedef __attribute__((ext_vector_type(2))) unsigned int  u32x2;

static __device__ __forceinline__ unsigned short f2bf(float f){
  union{float f; unsigned int u;} v; v.f=f;
  unsigned int r = v.u + 0x7fffu + ((v.u>>16)&1u);
  return (unsigned short)(r>>16);
}
static __device__ __forceinline__ float bf2f(unsigned short u){
  union{unsigned int i; float f;} v; v.i = ((unsigned int)u)<<16; return v.f;
}
static __device__ __forceinline__ void gload_lds16(const void* g, void* l){
  __builtin_amdgcn_global_load_lds((const __attribute__((address_space(1))) void*)g,
                                   (__attribute__((address_space(3))) void*)l, 16, 0, 0);
}

// ---------------- elementwise cast f32 -> bf16 ----------------
__global__ void cast_f32_bf16(const float* __restrict__ src, unsigned short* __restrict__ dst, int n){
  int i = (blockIdx.x*256 + threadIdx.x)*4;
  if (i >= n) return;
  f32x4 v = *reinterpret_cast<const f32x4*>(&src[i]);
  ushort4v o;
  o[0]=f2bf(v[0]); o[1]=f2bf(v[1]); o[2]=f2bf(v[2]); o[3]=f2bf(v[3]);
  *reinterpret_cast<ushort4v*>(&dst[i]) = o;
}

// ---------------- tiled transpose + cast: src[R][C] f32 -> dst[C][R] bf16 ----------------
__global__ void transpose_cast(const float* __restrict__ src, unsigned short* __restrict__ dst, int R, int C){
  __shared__ unsigned short tile[32][33];
  int c0 = blockIdx.x*32, r0 = blockIdx.y*32;
  int tx = threadIdx.x, ty = threadIdx.y;   // 32 x 8
  #pragma unroll
  for (int i=0;i<4;i++){
    int r = r0 + ty + i*8;
    tile[ty+i*8][tx] = f2bf(src[(size_t)r*C + c0 + tx]);
  }
  __syncthreads();
  #pragma unroll
  for (int i=0;i<4;i++){
    int c = c0 + ty + i*8;
    dst[(size_t)c*R + r0 + tx] = tile[tx][ty+i*8];
  }
}

// ---------------- per-head V transpose: qkv[n][2*DM + h*80 + d] -> Vt[h][d][n] ----------------
__global__ void transpose_v(const unsigned short* __restrict__ qkv, unsigned short* __restrict__ Vt){
  __shared__ unsigned short tile[32][33];
  int n0 = blockIdx.x*32, d0 = blockIdx.y*32, h = blockIdx.z;
  int tx = threadIdx.x, ty = threadIdx.y;   // 32 x 8
  #pragma unroll
  for (int i=0;i<4;i++){
    int n = n0 + ty + i*8;
    int d = d0 + tx;
    tile[ty+i*8][tx] = (d < HD) ? qkv[(size_t)n*QKVC + 2*DM + h*HD + d] : (unsigned short)0;
  }
  __syncthreads();
  #pragma unroll
  for (int i=0;i<4;i++){
    int d = d0 + ty + i*8;
    if (d < HD) Vt[((size_t)h*HD + d)*NTOK + n0 + tx] = tile[tx][ty+i*8];
  }
}

// ---------------- 2-phase pipelined bf16 GEMM: C = A[M][Kd] * Bt[Ncol][Kd]^T + bias ----------------
// 1D grid, XCD chunking + GROUP_M=8 grouped CTA mapping:
//   8 consecutive ids share one B panel (L2-resident) and a 2.6 MB A-slab ->
//   chip-wide staged traffic ~37 MB instead of ~240 MB (bm-major).
template<int OUT_BF16>
__global__ __launch_bounds__(256) void gemm_bt(
    const unsigned short* __restrict__ A,
    const unsigned short* __restrict__ Bt,
    const float* __restrict__ bias,
    unsigned short* __restrict__ Cb,
    float* __restrict__ Cf,
    int M, int Ncol, int Kd, int nbn)
{
  __shared__ unsigned short As[2][128*32];
  __shared__ unsigned short Bs[2][128*32];
  const int tid  = threadIdx.x;
  const int lane = tid & 63, wave = tid >> 6;
  const int wr = wave >> 1, wc = wave & 1;
  const int cpx = gridDim.x >> 3;
  const int id  = (blockIdx.x & 7)*cpx + (blockIdx.x >> 3);
  const int gsz = 8*nbn;
  const int g   = id / gsz, rem = id % gsz;
  const int bm  = g*8 + (rem & 7);
  const int bn  = rem >> 3;
  const f32x4 vzero = {0.f,0.f,0.f,0.f};

  f32x4 acc[4][4];
  #pragma unroll
  for (int i=0;i<4;i++)
    #pragma unroll
    for (int j=0;j<4;j++) acc[i][j] = vzero;

  const int rsub = lane>>2;          // 0..15
  const int kc   = (lane&3)*8;       // 0,8,16,24
  const unsigned short* Ab = A  + (size_t)(bm*128 + wave*32 + rsub)*Kd + kc;
  const unsigned short* Bb = Bt + (size_t)(bn*128 + wave*32 + rsub)*Kd + kc;

  // prologue: stage tile 0
  #pragma unroll
  for (int i=0;i<2;i++){
    gload_lds16(Ab + (size_t)i*16*Kd, &As[0][(wave*2+i)*512]);
    gload_lds16(Bb + (size_t)i*16*Kd, &Bs[0][(wave*2+i)*512]);
  }
  __syncthreads();

  int cur = 0;
  for (int k0=32; k0<Kd; k0+=32){
    #pragma unroll
    for (int i=0;i<2;i++){
      gload_lds16(Ab + (size_t)i*16*Kd + k0, &As[cur^1][(wave*2+i)*512]);
      gload_lds16(Bb + (size_t)i*16*Kd + k0, &Bs[cur^1][(wave*2+i)*512]);
    }
    bf16x8 a[4], b[4];
    #pragma unroll
    for (int mf=0; mf<4; mf++)
      a[mf] = *reinterpret_cast<const bf16x8*>(&As[cur][(wr*64 + mf*16 + (lane&15))*32 + ((lane>>4)<<3)]);
    #pragma unroll
    for (int nf=0; nf<4; nf++)
      b[nf] = *reinterpret_cast<const bf16x8*>(&Bs[cur][(wc*64 + nf*16 + (lane&15))*32 + ((lane>>4)<<3)]);
    #pragma unroll
    for (int mf=0; mf<4; mf++)
      #pragma unroll
      for (int nf=0; nf<4; nf++)
        acc[mf][nf] = __builtin_amdgcn_mfma_f32_16x16x32_bf16(a[mf], b[nf], acc[mf][nf], 0,0,0);
    __syncthreads();
    cur ^= 1;
  }
  { // final tile
    bf16x8 a[4], b[4];
    #pragma unroll
    for (int mf=0; mf<4; mf++)
      a[mf] = *reinterpret_cast<const bf16x8*>(&As[cur][(wr*64 + mf*16 + (lane&15))*32 + ((lane>>4)<<3)]);
    #pragma unroll
    for (int nf=0; nf<4; nf++)
      b[nf] = *reinterpret_cast<const bf16x8*>(&Bs[cur][(wc*64 + nf*16 + (lane&15))*32 + ((lane>>4)<<3)]);
    #pragma unroll
    for (int mf=0; mf<4; mf++)
      #pragma unroll
      for (int nf=0; nf<4; nf++)
        acc[mf][nf] = __builtin_amdgcn_mfma_f32_16x16x32_bf16(a[mf], b[nf], acc[mf][nf], 0,0,0);
  }

  const int crow0 = bm*128 + wr*64;
  const int ccol0 = bn*128 + wc*64;
  #pragma unroll
  for (int nf=0; nf<4; nf++){
    int col = ccol0 + nf*16 + (lane&15);
    float bv = bias[col];
    #pragma unroll
    for (int mf=0; mf<4; mf++){
      #pragma unroll
      for (int r=0;r<4;r++){
        int row = crow0 + mf*16 + ((lane>>4)<<2) + r;
        float v = acc[mf][nf][r] + bv;
        if (OUT_BF16) Cb[(size_t)row*Ncol + col] = f2bf(v);
        else          Cf[(size_t)row*Ncol + col] = v;
      }
    }
  }
}

// ---------------- RoPE + repack to [H][N][96], vectorized 8 elems/thread ----------------
// chunk c (8 elems): c 0..4 -> k<40 (pair +40, sgn -1); c 5..9 -> k in [40,80) (pair -40, sgn +1); c 10..11 -> zero pad
__global__ void rope_repack(const unsigned short* __restrict__ qkv,
                            const float* __restrict__ cosNK, const float* __restrict__ sinNK,
                            unsigned short* __restrict__ Qr, unsigned short* __restrict__ Kr)
{
  int idx = blockIdx.x*256 + threadIdx.x;
  if (idx >= NH*NTOK*12) return;
  int c  = idx % 12;
  int nh = idx / 12;
  int n  = nh % NTOK;
  int h  = nh / NTOK;
  unsigned short* qd = Qr + (size_t)(h*NTOK + n)*HDS + c*8;
  unsigned short* kd = Kr + (size_t)(h*NTOK + n)*HDS + c*8;
  if (c >= 10){
    ushort8 z = {0,0,0,0,0,0,0,0};
    *reinterpret_cast<ushort8*>(qd) = z;
    *reinterpret_cast<ushort8*>(kd) = z;
    return;
  }
  const int k0  = c*8;
  const int kp0 = (k0 < 40) ? (k0+40) : (k0-40);
  const float sgn = (k0 < 40) ? -1.f : 1.f;
  const size_t base = (size_t)n*QKVC + h*HD;
  ushort8 q  = *reinterpret_cast<const ushort8*>(&qkv[base + k0]);
  ushort8 qp = *reinterpret_cast<const ushort8*>(&qkv[base + kp0]);
  ushort8 kk = *reinterpret_cast<const ushort8*>(&qkv[base + DM + k0]);
  ushort8 kp = *reinterpret_cast<const ushort8*>(&qkv[base + DM + kp0]);
  f32x4 c0 = *reinterpret_cast<const f32x4*>(&cosNK[n*HD + k0]);
  f32x4 c1 = *reinterpret_cast<const f32x4*>(&cosNK[n*HD + k0 + 4]);
  f32x4 s0 = *reinterpret_cast<const f32x4*>(&sinNK[n*HD + k0]);
  f32x4 s1 = *reinterpret_cast<const f32x4*>(&sinNK[n*HD + k0 + 4]);
  ushort8 qo, ko;
  #pragma unroll
  for (int j=0;j<8;j++){
    float cj = (j<4) ? c0[j] : c1[j-4];
    float sj = (j<4) ? s0[j] : s1[j-4];
    qo[j] = f2bf(bf2f(q[j])*cj  + sgn*bf2f(qp[j])*sj);
    ko[j] = f2bf(bf2f(kk[j])*cj + sgn*bf2f(kp[j])*sj);
  }
  *reinterpret_cast<ushort8*>(qd) = qo;
  *reinterpret_cast<ushort8*>(kd) = ko;
}

// ---------------- segment-masked flash attention: swapped QK^T, lane-local softmax,
// ---------------- 2D balanced grid, 4 waves, per-wave k-range, no main-loop barriers ----------------
__global__ __launch_bounds__(256) void attn_kernel(
    const unsigned short* __restrict__ Qr,
    const unsigned short* __restrict__ Kr,
    const unsigned short* __restrict__ Vt,
    const int* __restrict__ cu,
    unsigned short* __restrict__ attn_out)
{
  __shared__ unsigned short Ps[4*16*KVB];   // 8 KB: per-wave 2 KB slice (16 rows x 64 k), XOR-swizzled

  const int h   = blockIdx.y;
  const int q0  = blockIdx.x*64;
  const int tid = threadIdx.x;
  const int lane = tid & 63, wave = tid >> 6;   // wave = q-slice 0..3
  const int l16 = lane & 15, g16 = lane >> 4;
  const int qrow = q0 + wave*16 + l16;          // this lane's q-row
  const f32x4 vzero = {0.f,0.f,0.f,0.f};

  // per-lane segment bounds + per-WAVE k-range (this wave's 16 rows only)
  const int rowA = q0 + wave*16, rowB = rowA + 15;
  int seg = 0, sA = 0, sB = 0;
  #pragma unroll
  for (int j=1;j<NSEG;j++){
    int c = cu[j];
    seg += (c <= qrow) ? 1 : 0;
    sA  += (c <= rowA) ? 1 : 0;
    sB  += (c <= rowB) ? 1 : 0;
  }
  const int rst = cu[seg], ren = cu[seg+1];
  const int kminW = cu[sA], kmaxW = cu[sB+1];
  const int kt0w = kminW & ~(KVB-1);

  // Q fragments in registers (B-operand: row = own q, k-slice = g16*8)
  bf16x8 bq[3];
  {
    const unsigned short* qsrc = Qr + ((size_t)h*NTOK + qrow)*HDS;
    #pragma unroll
    for (int ds=0; ds<3; ds++)
      bq[ds] = *reinterpret_cast<const bf16x8*>(&qsrc[ds*32 + g16*8]);
  }

  f32x4 accO[5];
  #pragma unroll
  for (int i=0;i<5;i++) accO[i] = vzero;
  float m_r = -1e30f, l_r = 0.f;
  const float scale = 0.11180339887498948f;  // 1/sqrt(80)

  char* const psb = (char*)Ps + wave*2048;   // wave-private 16x64 bf16 slice
  const int pswz  = (l16 & 7) << 4;

  for (int kt = kt0w; kt < kmaxW; kt += KVB){
    // V fragments (A-operand: row = d, k-slice = g16*8) — issue early, use late
    ushort8 vreg[2][5];
    #pragma unroll
    for (int ks=0; ks<2; ks++)
      #pragma unroll
      for (int cf=0; cf<5; cf++)
        vreg[ks][cf] = *reinterpret_cast<const ushort8*>(
            &Vt[((size_t)h*HD + cf*16 + l16)*NTOK + kt + ks*32 + g16*8]);

    // S^T = K Q^T : accST[f] rows k = f*16 + g16*4 + r, col q = l16
    const unsigned short* ksrc = Kr + ((size_t)h*NTOK + kt)*HDS;
    f32x4 accST[4];
    #pragma unroll
    for (int i=0;i<4;i++) accST[i] = vzero;
    #pragma unroll
    for (int ds=0; ds<3; ds++){
      #pragma unroll
      for (int f=0; f<4; f++){
        bf16x8 ak = *reinterpret_cast<const bf16x8*>(&ksrc[(size_t)(f*16 + l16)*HDS + ds*32 + g16*8]);
        accST[f] = __builtin_amdgcn_mfma_f32_16x16x32_bf16(ak, bq[ds], accST[f], 0,0,0);
      }
    }

    // lane-local masked online softmax (row = qrow; 16 scores per lane)
    float mx = -1e30f;
    #pragma unroll
    for (int f=0; f<4; f++){
      #pragma unroll
      for (int r=0; r<4; r++){
        int kcol = kt + f*16 + g16*4 + r;
        bool ok = (kcol >= rst) && (kcol < ren);
        float s = accST[f][r]*scale;
        accST[f][r] = ok ? s : -3e38f;       // sentinel: exp(sent - mnew) == 0 exactly
        mx = fmaxf(mx, accST[f][r]);
      }
    }
    mx = fmaxf(mx, __shfl_xor(mx, 16));
    mx = fmaxf(mx, __shfl_xor(mx, 32));
    const float mnew  = fmaxf(m_r, mx);
    const float alpha = __expf(m_r - mnew);
    m_r = mnew;
    float lsum = 0.f;
    #pragma unroll
    for (int f=0; f<4; f++){
      #pragma unroll
      for (int r=0; r<4; r++){
        float e = __expf(accST[f][r] - mnew);
        accST[f][r] = e;
        lsum += e;
      }
    }
    lsum += __shfl_xor(lsum, 16);
    lsum += __shfl_xor(lsum, 32);
    l_r = l_r*alpha + lsum;
    #pragma unroll
    for (int cf=0; cf<5; cf++) accO[cf] *= alpha;

    // P -> Ps (bf16, wave-private, swizzled): lane writes k = 16f + 4*g16 + 0..3 of row l16
    #pragma unroll
    for (int f=0; f<4; f++){
      u32x2 pk;
      pk[0] = (unsigned int)f2bf(accST[f][0]) | ((unsigned int)f2bf(accST[f][1]) << 16);
      pk[1] = (unsigned int)f2bf(accST[f][2]) | ((unsigned int)f2bf(accST[f][3]) << 16);
      *reinterpret_cast<u32x2*>(psb + ((l16*128 + f*32 + g16*8) ^ pswz)) = pk;
    }

    // O^T += V^T P^T : a = Vt rows (d), b = Ps rows (own q), out D[d][q]
    #pragma unroll
    for (int ks=0; ks<2; ks++){
      bf16x8 bp = *reinterpret_cast<const bf16x8*>(psb + ((l16*128 + ks*64 + g16*16) ^ pswz));
      #pragma unroll
      for (int cf=0; cf<5; cf++){
        bf16x8 av = __builtin_bit_cast(bf16x8, vreg[ks][cf]);
        accO[cf] = __builtin_amdgcn_mfma_f32_16x16x32_bf16(av, bp, accO[cf], 0,0,0);
      }
    }
  }

  // epilogue: lane holds O[qrow][d = cf*16 + g16*4 + r] -> packed 8B stores
  const float inv = 1.f / l_r;
  #pragma unroll
  for (int cf=0; cf<5; cf++){
    ushort4v o;
    #pragma unroll
    for (int r=0;r<4;r++) o[r] = f2bf(accO[cf][r]*inv);
    *reinterpret_cast<ushort4v*>(&attn_out[(size_t)qrow*DM + h*HD + cf*16 + g16*4]) = o;
  }
}

extern "C" void kernel_launch(void* const* d_in, const int* in_sizes, int n_in,
                              void* d_out, int out_size, void* d_ws, size_t ws_size,
                              hipStream_t stream)
{
  const float* hidden = (const float*)d_in[0];
  const int*   cu     = (const int*)  d_in[1];
  const float* cosNK  = (const float*)d_in[2];
  const float* sinNK  = (const float*)d_in[3];
  const float* qkv_w  = (const float*)d_in[4];
  const float* qkv_b  = (const float*)d_in[5];
  const float* proj_w = (const float*)d_in[6];
  const float* proj_b = (const float*)d_in[7];
  float* out = (float*)d_out;

  char* w = (char*)d_ws;
  unsigned short* hid_bf  = (unsigned short*)w;  w += (size_t)NTOK*DM*2;      // aliased by attn_bf later
  unsigned short* qkvwT   = (unsigned short*)w;  w += (size_t)QKVC*DM*2;      // aliased by Vt later
  unsigned short* projwT  = (unsigned short*)w;  w += (size_t)DM*DM*2;
  unsigned short* qkv_bf  = (unsigned short*)w;  w += (size_t)NTOK*QKVC*2;
  unsigned short* Qr      = (unsigned short*)w;  w += (size_t)NH*NTOK*HDS*2;
  unsigned short* Kr      = (unsigned short*)w;  w += (size_t)NH*NTOK*HDS*2;
  unsigned short* Vt      = qkvwT;    // reuse: qkvwT dead after QKV GEMM
  unsigned short* attn_bf = hid_bf;   // reuse: hid_bf dead after QKV GEMM

  cast_f32_bf16<<<(NTOK*DM/4 + 255)/256, 256, 0, stream>>>(hidden, hid_bf, NTOK*DM);
  transpose_cast<<<dim3(QKVC/32, DM/32), dim3(32,8), 0, stream>>>(qkv_w, qkvwT, DM, QKVC);
  transpose_cast<<<dim3(DM/32,  DM/32), dim3(32,8), 0, stream>>>(proj_w, projwT, DM, DM);
  gemm_bt<1><<<dim3((NTOK/128)*(QKVC/128)), 256, 0, stream>>>(hid_bf, qkvwT, qkv_b, qkv_bf, nullptr, NTOK, QKVC, DM, QKVC/128);
  rope_repack<<<(NH*NTOK*12 + 255)/256, 256, 0, stream>>>(qkv_bf, cosNK, sinNK, Qr, Kr);
  transpose_v<<<dim3(NTOK/32, 3, NH), dim3(32,8), 0, stream>>>(qkv_bf, Vt);
  attn_kernel<<<dim3(NTOK/64, NH), 256, 0, stream>>>(Qr, Kr, Vt, cu, attn_bf);
  gemm_bt<0><<<dim3((NTOK/128)*(DM/128)), 256, 0, stream>>>(attn_bf, projwT, proj_b, nullptr, out, NTOK, DM, DM, DM/128);
}